// Round 1
// baseline (254.113 us; speedup 1.0000x reference)
//
#include <hip/hip_runtime.h>
#include <math.h>

#define BB 1024
#define NN 4096
#define HH 32

// One workgroup per batch. 256 threads = 4 waves.
// Pass 1: stream ne[b] (512 KB) -> column sums -> avg; tiny MLP -> qk[b] (32 floats, in LDS).
// Pass 2: stream ne[b] again -> scores into LDS -> softmax -> out.
__global__ __launch_bounds__(256) void gnd_kernel(
    const float* __restrict__ ne,     // [B,N,H]
    const float* __restrict__ mask,   // [B,N]
    const float* __restrict__ times,  // [B]
    const float* __restrict__ W1,     // [H, 2H+1] row-major
    const float* __restrict__ b1,     // [H]
    const float* __restrict__ Wq,     // [H,H]
    const float* __restrict__ Wk,     // [H,H]
    const int*   __restrict__ idxc,   // [B]
    float* __restrict__ out)          // [B,N]
{
    const int b   = blockIdx.x;
    const int tid = threadIdx.x;
    const int q8  = tid & 7;   // which float4 within a 32-float row
    const int r   = tid >> 3;  // row within group of 32

    __shared__ float s_lds[NN];      // 16 KB: partial stage, then scores, then exp
    __shared__ float sh_avg[HH];     // column sums -> avg
    __shared__ float sh_f[HH];       // gathered context row, later reused for q
    __shared__ float sh_emb[HH];
    __shared__ float sh_qk[HH];
    __shared__ float red_buf[4];     // 4 waves

    const float* nb = ne + (size_t)b * (NN * HH);

    // ---------------- pass 1: column sums over N ----------------
    float a0 = 0.f, a1 = 0.f, a2 = 0.f, a3 = 0.f;
    #pragma unroll 4
    for (int n = r; n < NN; n += 32) {
        const float4 v = *reinterpret_cast<const float4*>(nb + n * HH + q8 * 4);
        a0 += v.x; a1 += v.y; a2 += v.z; a3 += v.w;
    }
    *reinterpret_cast<float4*>(&s_lds[tid * 4]) = make_float4(a0, a1, a2, a3);

    // gather f = ne[b, idxc[b], :] (wave 1, overlaps staging)
    if (tid >= 64 && tid < 64 + HH) {
        sh_f[tid - 64] = nb[(size_t)idxc[b] * HH + (tid - 64)];
    }
    __syncthreads();

    // deterministic fixed-order reduce: thread h sums its column's 32 partials
    if (tid < HH) {
        const int q = tid >> 2, j = tid & 3;
        float s = 0.f;
        #pragma unroll
        for (int rr = 0; rr < 32; ++rr) s += s_lds[(rr * 8 + q) * 4 + j];
        sh_avg[tid] = s;  // raw sum; /N applied below
    }
    __syncthreads();

    // ---------------- tiny MLP: emb -> q -> qk ----------------
    if (tid < HH) {
        const float invN = 1.0f / (float)NN;
        const float t = times[b];
        const float* w = W1 + tid * (2 * HH + 1);
        float e = b1[tid];
        #pragma unroll
        for (int j = 0; j < HH; ++j) e += (sh_avg[j] * invN) * w[j];
        #pragma unroll
        for (int j = 0; j < HH; ++j) e += sh_f[j] * w[HH + j];
        e += t * w[2 * HH];
        sh_emb[tid] = e;
    }
    __syncthreads();
    if (tid < HH) {  // q = emb @ Wq^T   (store into sh_f, no longer needed)
        const float* w = Wq + tid * HH;
        float qv = 0.f;
        #pragma unroll
        for (int j = 0; j < HH; ++j) qv += sh_emb[j] * w[j];
        sh_f[tid] = qv;
    }
    __syncthreads();
    if (tid < HH) {  // qk[j] = sum_h q[h] * Wk[h,j], scaled by 1/sqrt(H)
        float s = 0.f;
        #pragma unroll
        for (int h = 0; h < HH; ++h) s += sh_f[h] * Wk[h * HH + tid];
        sh_qk[tid] = s * 0.17677669529663687f;  // 1/sqrt(32)
    }
    __syncthreads();

    // ---------------- pass 2: scores ----------------
    const float kq0 = sh_qk[q8 * 4 + 0];
    const float kq1 = sh_qk[q8 * 4 + 1];
    const float kq2 = sh_qk[q8 * 4 + 2];
    const float kq3 = sh_qk[q8 * 4 + 3];
    const float* mrow = mask + (size_t)b * NN;

    float lmax = -INFINITY;
    #pragma unroll 4
    for (int n = r; n < NN; n += 32) {
        const float4 v = *reinterpret_cast<const float4*>(nb + n * HH + q8 * 4);
        float p = v.x * kq0 + v.y * kq1 + v.z * kq2 + v.w * kq3;
        p += __shfl_xor(p, 1);
        p += __shfl_xor(p, 2);
        p += __shfl_xor(p, 4);
        if (q8 == 0) {
            const float sc = p - mrow[n] * 999999999.0f;
            s_lds[n] = sc;
            lmax = fmaxf(lmax, sc);
        }
    }

    // ---------------- softmax ----------------
    // block max (lanes with q8!=0 hold -inf, harmless)
    #pragma unroll
    for (int m = 1; m < 64; m <<= 1) lmax = fmaxf(lmax, __shfl_xor(lmax, m));
    __syncthreads();                       // s_lds scores fully written
    if ((tid & 63) == 0) red_buf[tid >> 6] = lmax;
    __syncthreads();
    const float bmax = fmaxf(fmaxf(red_buf[0], red_buf[1]),
                             fmaxf(red_buf[2], red_buf[3]));

    float lsum = 0.f;
    for (int n = tid; n < NN; n += 256) {
        const float e = expf(s_lds[n] - bmax);
        s_lds[n] = e;
        lsum += e;
    }
    #pragma unroll
    for (int m = 1; m < 64; m <<= 1) lsum += __shfl_xor(lsum, m);
    __syncthreads();                       // red_buf reads done
    if ((tid & 63) == 0) red_buf[tid >> 6] = lsum;
    __syncthreads();
    const float inv = 1.0f / (red_buf[0] + red_buf[1] + red_buf[2] + red_buf[3]);

    float* orow = out + (size_t)b * NN;
    for (int n = tid; n < NN; n += 256) {
        orow[n] = s_lds[n] * inv;
    }
}

extern "C" void kernel_launch(void* const* d_in, const int* in_sizes, int n_in,
                              void* d_out, int out_size, void* d_ws, size_t ws_size,
                              hipStream_t stream) {
    (void)in_sizes; (void)n_in; (void)d_ws; (void)ws_size; (void)out_size;
    const float* ne    = (const float*)d_in[0];
    const float* mask  = (const float*)d_in[1];
    const float* times = (const float*)d_in[2];
    // d_in[3] = vf, unused (idxc path taken)
    const float* W1    = (const float*)d_in[4];
    const float* b1    = (const float*)d_in[5];
    const float* Wq    = (const float*)d_in[6];
    const float* Wk    = (const float*)d_in[7];
    const int*   idxc  = (const int*)d_in[8];
    float* out = (float*)d_out;

    gnd_kernel<<<dim3(BB), dim3(256), 0, stream>>>(
        ne, mask, times, W1, b1, Wq, Wk, idxc, out);
}